// Round 10
// baseline (468.221 us; speedup 1.0000x reference)
//
#include <hip/hip_runtime.h>
#include <math.h>

#define NN   2048
#define BB   16
#define CINC 2
#define HID  64
#define C1   66
#define NC   1056      // 16*66
#define NCP  1152      // padded col dim
#define KI   132       // contraction length
#define KIP  168       // LDS A row pitch (u16)
#define KS   5         // K fragments of 32 (132 -> 160 padded)

typedef unsigned short u16;
typedef __attribute__((ext_vector_type(8))) short bf16x8;
typedef __attribute__((ext_vector_type(4))) float f32x4;

__device__ __forceinline__ u16 f2bf(float f) {
    union { float f; unsigned int u; } v; v.f = f;
    unsigned int r = (v.u + 0x7FFFu + ((v.u >> 16) & 1u)) >> 16;
    return (u16)r;
}

// ---------------------------------------------------------------------------
// S_bf[n][m] = softmax_m(relu(E@E^T)) in bf16
// ---------------------------------------------------------------------------
__global__ __launch_bounds__(256) void support_softmax(const float* __restrict__ E,
                                                       u16* __restrict__ S)
{
    const int n = blockIdx.x, t = threadIdx.x;
    __shared__ float red[4];
    float en[16];
#pragma unroll
    for (int d = 0; d < 16; ++d) en[d] = E[n * 16 + d];

    float v[8]; float mx = 0.f;
#pragma unroll
    for (int j = 0; j < 8; ++j) {
        const int m = t + j * 256;
        const float4* ep = (const float4*)&E[m * 16];
        float4 e0 = ep[0], e1 = ep[1], e2 = ep[2], e3 = ep[3];
        float dot = en[0]*e0.x + en[1]*e0.y + en[2]*e0.z + en[3]*e0.w
                  + en[4]*e1.x + en[5]*e1.y + en[6]*e1.z + en[7]*e1.w
                  + en[8]*e2.x + en[9]*e2.y + en[10]*e2.z + en[11]*e2.w
                  + en[12]*e3.x + en[13]*e3.y + en[14]*e3.z + en[15]*e3.w;
        dot = fmaxf(dot, 0.f);
        v[j] = dot; mx = fmaxf(mx, dot);
    }
#pragma unroll
    for (int off = 32; off; off >>= 1) mx = fmaxf(mx, __shfl_down(mx, off, 64));
    const int wid = t >> 6, lane = t & 63;
    if (lane == 0) red[wid] = mx;
    __syncthreads();
    mx = fmaxf(fmaxf(red[0], red[1]), fmaxf(red[2], red[3]));

    float s = 0.f;
#pragma unroll
    for (int j = 0; j < 8; ++j) { v[j] = expf(v[j] - mx); s += v[j]; }
#pragma unroll
    for (int off = 32; off; off >>= 1) s += __shfl_down(s, off, 64);
    __syncthreads();
    if (lane == 0) red[wid] = s;
    __syncthreads();
    s = red[0] + red[1] + red[2] + red[3];
    const float inv = 1.f / s;
#pragma unroll
    for (int j = 0; j < 8; ++j) S[n * NN + t + j * 256] = f2bf(v[j] * inv);
}

// ---------------------------------------------------------------------------
// XcatT[j][m] (bf16, [1152][2048]); rows j>=1056 zero
// ---------------------------------------------------------------------------
__global__ __launch_bounds__(256) void build_xcatT(const float* __restrict__ X,
                                                   const float* __restrict__ state,
                                                   u16* __restrict__ XT)
{
    const int idx = blockIdx.x * 256 + threadIdx.x;
    const int m = idx & (NN - 1), j = idx >> 11;
    float val = 0.f;
    if (j < NC) {
        const int b = j / C1, c = j - b * C1;
        val = (c < CINC) ? X[(b * NN + m) * CINC + c]
                         : state[(b * NN + m) * HID + (c - CINC)];
    }
    XT[(size_t)j * NN + m] = f2bf(val);
}

// ---------------------------------------------------------------------------
// wbuild_sw<NCT>: Wsw[n][ct][ks][lane][8] bf16 fragment-swizzled per-node W.
// element (n,ct,ks,l,j) = sum_d E[n,d]*Wp[d][ki][o], ki=ks*32+(l>>4)*8+j,
// o=ct*16+(l&15); zero if ki>=132. 16 nodes per blockIdx.y.
// ---------------------------------------------------------------------------
template<int NCT>
__global__ __launch_bounds__(256) void wbuild_sw(const float* __restrict__ E,
                                                 const float* __restrict__ Wp,
                                                 u16* __restrict__ Wsw)
{
    const int t = threadIdx.x;
    const int slot = blockIdx.x * 256 + t;         // over NCT*5*64
    const int l = slot & 63, ks = (slot >> 6) % KS, ct = slot / (KS * 64);
    const int n0 = blockIdx.y * 16;
    const int O = NCT * 16;
    __shared__ float El[256];
    El[t] = E[n0 * 16 + t];
    __syncthreads();

    const int o = ct * 16 + (l & 15);
    const int kibase = ks * 32 + (l >> 4) * 8;

    uint4 pk[16];
#pragma unroll
    for (int jp = 0; jp < 4; ++jp) {
        const int ki0 = kibase + 2 * jp, ki1 = ki0 + 1;
        float w0[16], w1[16];
#pragma unroll
        for (int d = 0; d < 16; ++d) {
            w0[d] = (ki0 < KI) ? Wp[d * (KI * O) + ki0 * O + o] : 0.f;
            w1[d] = (ki1 < KI) ? Wp[d * (KI * O) + ki1 * O + o] : 0.f;
        }
#pragma unroll
        for (int g = 0; g < 16; ++g) {
            float s0 = 0.f, s1 = 0.f;
#pragma unroll
            for (int d = 0; d < 16; ++d) {
                const float e = El[g * 16 + d];
                s0 += e * w0[d]; s1 += e * w1[d];
            }
            unsigned int packed = (unsigned int)f2bf(s0) | ((unsigned int)f2bf(s1) << 16);
            ((unsigned int*)&pk[g])[jp] = packed;
        }
    }
#pragma unroll
    for (int g = 0; g < 16; ++g) {
        const size_t base = ((((size_t)(n0 + g) * NCT + ct) * KS + ks) * 64 + l) * 8;
        *(uint4*)&Wsw[base] = pk[g];
    }
}

// ---------------------------------------------------------------------------
// bf16 MFMA GEMM: C[2048][1152] = A[2048][2048] @ BT[1152][2048]^T
// 128x64 tile, BK=32, 4 waves (each 64x32 = 4x2 frags of 16x16x32)
// reg-staged LDS, pitch 40 u16 (2-way banks = free)
// ---------------------------------------------------------------------------
#define APITCH 40
__global__ __launch_bounds__(256) void gemm_bt(const u16* __restrict__ A,
                                               const u16* __restrict__ BT,
                                               u16* __restrict__ C)
{
    __shared__ u16 As[128 * APITCH];
    __shared__ u16 Bs[64 * APITCH];
    const int t = threadIdx.x, w = t >> 6, l = t & 63;
    const int m0 = blockIdx.y * 128, n0 = blockIdx.x * 64;
    const int wm = (w >> 1) * 64, wn = (w & 1) * 32;

    // staging map
    const int rA0 = t >> 2, rA1 = 64 + (t >> 2), qA = (t & 3) * 8;
    const int rB  = t >> 2;
    const size_t gA0 = (size_t)(m0 + rA0) * NN + qA;
    const size_t gA1 = (size_t)(m0 + rA1) * NN + qA;
    const size_t gB  = (size_t)(n0 + rB) * NN + qA;

    f32x4 acc[4][2];
#pragma unroll
    for (int i = 0; i < 4; ++i)
#pragma unroll
        for (int j = 0; j < 2; ++j) acc[i][j] = f32x4{0.f, 0.f, 0.f, 0.f};

    bf16x8 va0 = *(const bf16x8*)&A[gA0];
    bf16x8 va1 = *(const bf16x8*)&A[gA1];
    bf16x8 vb  = *(const bf16x8*)&BT[gB];

    for (int k0 = 0; k0 < NN; k0 += 32) {
        *(bf16x8*)&As[rA0 * APITCH + qA] = va0;
        *(bf16x8*)&As[rA1 * APITCH + qA] = va1;
        *(bf16x8*)&Bs[rB  * APITCH + qA] = vb;
        __syncthreads();
        if (k0 + 32 < NN) {
            va0 = *(const bf16x8*)&A[gA0 + k0 + 32];
            va1 = *(const bf16x8*)&A[gA1 + k0 + 32];
            vb  = *(const bf16x8*)&BT[gB + k0 + 32];
        }
        bf16x8 af[4], bfr[2];
#pragma unroll
        for (int mi = 0; mi < 4; ++mi)
            af[mi] = *(const bf16x8*)&As[(wm + mi * 16 + (l & 15)) * APITCH + (l >> 4) * 8];
#pragma unroll
        for (int nj = 0; nj < 2; ++nj)
            bfr[nj] = *(const bf16x8*)&Bs[(wn + nj * 16 + (l & 15)) * APITCH + (l >> 4) * 8];
#pragma unroll
        for (int mi = 0; mi < 4; ++mi)
#pragma unroll
            for (int nj = 0; nj < 2; ++nj)
                acc[mi][nj] = __builtin_amdgcn_mfma_f32_16x16x32_bf16(af[mi], bfr[nj], acc[mi][nj], 0, 0, 0);
        __syncthreads();
    }
#pragma unroll
    for (int mi = 0; mi < 4; ++mi)
#pragma unroll
        for (int nj = 0; nj < 2; ++nj)
#pragma unroll
            for (int q = 0; q < 4; ++q) {
                const int row = m0 + wm + mi * 16 + (l >> 4) * 4 + q;
                const int col = n0 + wn + nj * 16 + (l & 15);
                C[(size_t)row * NCP + col] = f2bf(acc[mi][nj][q]);
            }
}

// ---------------------------------------------------------------------------
// Gate apply: 4 nodes/block (1 wave each). A[16x132] in LDS (zero-padded),
// B-frags = coalesced b128 from Wsw. Bias fused. z*state->candRow, r->rbuf(bf16)
// ---------------------------------------------------------------------------
__global__ __launch_bounds__(256) void apply_gate(const u16* __restrict__ Wg,
                                                  const float* __restrict__ E,
                                                  const float* __restrict__ gb,
                                                  const float* __restrict__ X,
                                                  const float* __restrict__ state,
                                                  const u16* __restrict__ Zg,
                                                  u16* __restrict__ candRow,
                                                  u16* __restrict__ rbuf)
{
    const int t = threadIdx.x, wv = t >> 6, l = t & 63;
    const int node = blockIdx.x * 4 + wv;
    __shared__ u16 Al[4][16 * KIP];
    __shared__ float biasw[4][128];
    u16* base = Al[wv];

    // bias for this node
    {
        float b0 = 0.f, b1 = 0.f;
#pragma unroll
        for (int d = 0; d < 16; ++d) {
            const float e = E[node * 16 + d];
            b0 += e * gb[d * 128 + l];
            b1 += e * gb[d * 128 + 64 + l];
        }
        biasw[wv][l] = b0; biasw[wv][l + 64] = b1;
    }

    for (int i = l; i < 16 * KIP; i += 64) base[i] = 0;
    for (int f = l; f < 32; f += 64) {
        const int b = f >> 1, c = f & 1;
        base[b * KIP + c] = f2bf(X[(b * NN + node) * CINC + c]);
    }
#pragma unroll
    for (int k = 0; k < 16; ++k)
        base[k * KIP + 2 + l] = f2bf(state[(k * NN + node) * HID + l]);
    for (int f = l; f < NC; f += 64) {
        const int b = f / C1, i = f - b * C1;
        base[b * KIP + C1 + i] = Zg[(size_t)node * NCP + f];
    }
    __syncthreads();

    bf16x8 aF[KS];
#pragma unroll
    for (int kc = 0; kc < KS; ++kc)
        aF[kc] = *(const bf16x8*)&base[(l & 15) * KIP + kc * 32 + (l >> 4) * 8];

    const u16* wp_n = Wg + (((size_t)node * 8) * KS) * 512;
#pragma unroll 2
    for (int ct = 0; ct < 8; ++ct) {
        f32x4 acc = f32x4{0.f, 0.f, 0.f, 0.f};
#pragma unroll
        for (int kc = 0; kc < KS; ++kc) {
            bf16x8 bF = *(const bf16x8*)&wp_n[(((size_t)ct * KS + kc) * 64 + l) * 8];
            acc = __builtin_amdgcn_mfma_f32_16x16x32_bf16(aF[kc], bF, acc, 0, 0, 0);
        }
#pragma unroll
        for (int q = 0; q < 4; ++q) {
            const int b = (l >> 4) * 4 + q;
            const int o = ct * 16 + (l & 15);
            const float y = acc[q] + biasw[wv][o];
            const float sg = 1.f / (1.f + expf(-y));
            if (o < 64) {
                candRow[(size_t)node * NCP + b * C1 + CINC + o] =
                    f2bf(sg * state[(b * NN + node) * HID + o]);
            } else {
                rbuf[((size_t)node * BB + b) * HID + (o - 64)] = f2bf(sg);
            }
        }
    }
    for (int f = l; f < 32; f += 64) {
        const int b = f >> 1, c = f & 1;
        candRow[(size_t)node * NCP + b * C1 + c] = f2bf(X[(b * NN + node) * CINC + c]);
    }
}

// ---------------------------------------------------------------------------
// candT[j][m] = candRow[m][j]; rows j>=1056 zeroed
// ---------------------------------------------------------------------------
__global__ __launch_bounds__(256) void transpose_pad(const u16* __restrict__ in,
                                                     u16* __restrict__ out)
{
    __shared__ u16 tile[64][65];
    const int t = threadIdx.x;
    const int j0 = blockIdx.x * 64, m0 = blockIdx.y * 64;
    for (int r = t >> 6; r < 64; r += 4)
        tile[r][t & 63] = in[(size_t)(m0 + r) * NCP + j0 + (t & 63)];
    __syncthreads();
    for (int r = t >> 6; r < 64; r += 4) {
        const int j = j0 + r;
        const u16 val = (j < NC) ? tile[t & 63][r] : (u16)0;
        out[(size_t)j * NN + m0 + (t & 63)] = val;
    }
}

// ---------------------------------------------------------------------------
// Update apply + combine: hc=tanh(A@Wu+bias); h=r*state+(1-r)*hc
// ---------------------------------------------------------------------------
__global__ __launch_bounds__(256) void apply_upd(const u16* __restrict__ Wu,
                                                 const float* __restrict__ E,
                                                 const float* __restrict__ ub,
                                                 const u16* __restrict__ candRow,
                                                 const u16* __restrict__ Zu,
                                                 const float* __restrict__ state,
                                                 const u16* __restrict__ rbuf,
                                                 float* __restrict__ out)
{
    const int t = threadIdx.x, wv = t >> 6, l = t & 63;
    const int node = blockIdx.x * 4 + wv;
    __shared__ u16 Al[4][16 * KIP];
    __shared__ float biasw[4][64];
    u16* base = Al[wv];

    if (l < 64) {
        float b0 = 0.f;
#pragma unroll
        for (int d = 0; d < 16; ++d) b0 += E[node * 16 + d] * ub[d * 64 + l];
        biasw[wv][l] = b0;
    }

    for (int i = l; i < 16 * KIP; i += 64) base[i] = 0;
    for (int f = l; f < NC; f += 64) {
        const int b = f / C1, i = f - b * C1;
        base[b * KIP + i]      = candRow[(size_t)node * NCP + f];
        base[b * KIP + C1 + i] = Zu[(size_t)node * NCP + f];
    }
    __syncthreads();

    bf16x8 aF[KS];
#pragma unroll
    for (int kc = 0; kc < KS; ++kc)
        aF[kc] = *(const bf16x8*)&base[(l & 15) * KIP + kc * 32 + (l >> 4) * 8];

    const u16* wp_n = Wu + (((size_t)node * 4) * KS) * 512;
#pragma unroll 2
    for (int ct = 0; ct < 4; ++ct) {
        f32x4 acc = f32x4{0.f, 0.f, 0.f, 0.f};
#pragma unroll
        for (int kc = 0; kc < KS; ++kc) {
            bf16x8 bF = *(const bf16x8*)&wp_n[(((size_t)ct * KS + kc) * 64 + l) * 8];
            acc = __builtin_amdgcn_mfma_f32_16x16x32_bf16(aF[kc], bF, acc, 0, 0, 0);
        }
#pragma unroll
        for (int q = 0; q < 4; ++q) {
            const int b = (l >> 4) * 4 + q;
            const int o = ct * 16 + (l & 15);
            const float hc = tanhf(acc[q] + biasw[wv][o]);
            union { unsigned int u; float f; } rv;
            rv.u = ((unsigned int)rbuf[((size_t)node * BB + b) * HID + o]) << 16;
            const float r = rv.f;
            const float st = state[(b * NN + node) * HID + o];
            out[(size_t)(b * NN + node) * HID + o] = r * st + (1.f - r) * hc;
        }
    }
}

// ---------------------------------------------------------------------------
extern "C" void kernel_launch(void* const* d_in, const int* in_sizes, int n_in,
                              void* d_out, int out_size, void* d_ws, size_t ws_size,
                              hipStream_t stream)
{
    const float* X     = (const float*)d_in[0];
    const float* state = (const float*)d_in[1];
    const float* E     = (const float*)d_in[2];
    const float* gW    = (const float*)d_in[3];
    const float* gb    = (const float*)d_in[4];
    const float* uW    = (const float*)d_in[5];
    const float* ub    = (const float*)d_in[6];
    float* out = (float*)d_out;

    char* ws = (char*)d_ws;
    u16* S_bf  = (u16*)(ws);                    //  8,388,608
    u16* XcatT = (u16*)(ws + 8388608);          //  4,718,592 (reused as Zu)
    u16* Zg    = (u16*)(ws + 13107200);         //  4,718,592 (reused as candT)
    u16* candR = (u16*)(ws + 17825792);         //  4,718,592
    u16* rbuf  = (u16*)(ws + 22544384);         //  4,194,304
    u16* Wsw   = (u16*)(ws + 26738688);         // 83,886,080  -> total 110,624,768
    u16* candT = Zg;
    u16* Zu    = XcatT;

    support_softmax<<<NN, 256, 0, stream>>>(E, S_bf);
    build_xcatT<<<(NCP * NN) / 256, 256, 0, stream>>>(X, state, XcatT);
    wbuild_sw<8><<<dim3(10, 128), 256, 0, stream>>>(E, gW, Wsw);
    gemm_bt<<<dim3(NCP / 64, NN / 128), 256, 0, stream>>>(S_bf, XcatT, Zg);
    apply_gate<<<NN / 4, 256, 0, stream>>>(Wsw, E, gb, X, state, Zg, candR, rbuf);
    transpose_pad<<<dim3(NCP / 64, NN / 64), 256, 0, stream>>>(candR, candT);
    wbuild_sw<4><<<dim3(5, 128), 256, 0, stream>>>(E, uW, Wsw);
    gemm_bt<<<dim3(NCP / 64, NN / 128), 256, 0, stream>>>(S_bf, candT, Zu);
    apply_upd<<<NN / 4, 256, 0, stream>>>(Wsw, E, ub, candR, Zu, state, rbuf, out);
}

// Round 14
// 328.986 us; speedup vs baseline: 1.4232x; 1.4232x over previous
//
#include <hip/hip_runtime.h>
#include <math.h>

#define NN   2048
#define BB   16
#define CINC 2
#define HID  64
#define C1   66
#define NC   1056      // 16*66
#define NCP  1152      // padded col dim
#define KI   132       // contraction length
#define KIP  168       // LDS A row pitch (u16)
#define KS   5         // K fragments of 32 (132 -> 160 padded)

typedef unsigned short u16;
typedef __attribute__((ext_vector_type(8))) short bf16x8;
typedef __attribute__((ext_vector_type(4))) float f32x4;

__device__ __forceinline__ u16 f2bf(float f) {
    union { float f; unsigned int u; } v; v.f = f;
    unsigned int r = (v.u + 0x7FFFu + ((v.u >> 16) & 1u)) >> 16;
    return (u16)r;
}

// ---------------------------------------------------------------------------
// S_bf[n][m] = softmax_m(relu(E@E^T)) in bf16
// ---------------------------------------------------------------------------
__global__ __launch_bounds__(256) void support_softmax(const float* __restrict__ E,
                                                       u16* __restrict__ S)
{
    const int n = blockIdx.x, t = threadIdx.x;
    __shared__ float red[4];
    float en[16];
#pragma unroll
    for (int d = 0; d < 16; ++d) en[d] = E[n * 16 + d];

    float v[8]; float mx = 0.f;
#pragma unroll
    for (int j = 0; j < 8; ++j) {
        const int m = t + j * 256;
        const float4* ep = (const float4*)&E[m * 16];
        float4 e0 = ep[0], e1 = ep[1], e2 = ep[2], e3 = ep[3];
        float dot = en[0]*e0.x + en[1]*e0.y + en[2]*e0.z + en[3]*e0.w
                  + en[4]*e1.x + en[5]*e1.y + en[6]*e1.z + en[7]*e1.w
                  + en[8]*e2.x + en[9]*e2.y + en[10]*e2.z + en[11]*e2.w
                  + en[12]*e3.x + en[13]*e3.y + en[14]*e3.z + en[15]*e3.w;
        dot = fmaxf(dot, 0.f);
        v[j] = dot; mx = fmaxf(mx, dot);
    }
#pragma unroll
    for (int off = 32; off; off >>= 1) mx = fmaxf(mx, __shfl_down(mx, off, 64));
    const int wid = t >> 6, lane = t & 63;
    if (lane == 0) red[wid] = mx;
    __syncthreads();
    mx = fmaxf(fmaxf(red[0], red[1]), fmaxf(red[2], red[3]));

    float s = 0.f;
#pragma unroll
    for (int j = 0; j < 8; ++j) { v[j] = expf(v[j] - mx); s += v[j]; }
#pragma unroll
    for (int off = 32; off; off >>= 1) s += __shfl_down(s, off, 64);
    __syncthreads();
    if (lane == 0) red[wid] = s;
    __syncthreads();
    s = red[0] + red[1] + red[2] + red[3];
    const float inv = 1.f / s;
#pragma unroll
    for (int j = 0; j < 8; ++j) S[n * NN + t + j * 256] = f2bf(v[j] * inv);
}

// ---------------------------------------------------------------------------
// XcatT[j][m] (bf16, [1152][2048]); rows j>=1056 zero
// ---------------------------------------------------------------------------
__global__ __launch_bounds__(256) void build_xcatT(const float* __restrict__ X,
                                                   const float* __restrict__ state,
                                                   u16* __restrict__ XT)
{
    const int idx = blockIdx.x * 256 + threadIdx.x;
    const int m = idx & (NN - 1), j = idx >> 11;
    float val = 0.f;
    if (j < NC) {
        const int b = j / C1, c = j - b * C1;
        val = (c < CINC) ? X[(b * NN + m) * CINC + c]
                         : state[(b * NN + m) * HID + (c - CINC)];
    }
    XT[(size_t)j * NN + m] = f2bf(val);
}

// ---------------------------------------------------------------------------
// wbuild_sw<NCT>: Wsw[n][ct][ks][lane][8] bf16 fragment-swizzled per-node W.
// element (n,ct,ks,l,j) = sum_d E[n,d]*Wp[d][ki][o], ki=ks*32+(l>>4)*8+j,
// o=ct*16+(l&15); zero if ki>=132. G=8 nodes per blockIdx.y.
// NOTE: pk kept strictly register-resident (static unrolled indices only;
// no address-taking of locals -> no scratch). Round-10 version spilled
// ~1KB/thread via ((uint*)&pk[g])[jp], causing 345MB WRITE_SIZE.
// ---------------------------------------------------------------------------
template<int NCT>
__global__ __launch_bounds__(256) void wbuild_sw(const float* __restrict__ E,
                                                 const float* __restrict__ Wp,
                                                 u16* __restrict__ Wsw)
{
    const int G = 8;
    const int t = threadIdx.x;
    const int slot = blockIdx.x * 256 + t;         // over NCT*5*64
    const int l = slot & 63, ks = (slot >> 6) % KS, ct = slot / (KS * 64);
    const int n0 = blockIdx.y * G;
    const int O = NCT * 16;
    __shared__ float El[G * 16];
    if (t < G * 16) El[t] = E[n0 * 16 + t];
    __syncthreads();

    const int o = ct * 16 + (l & 15);
    const int kibase = ks * 32 + (l >> 4) * 8;

    unsigned int pk[G][4];
#pragma unroll
    for (int jp = 0; jp < 4; ++jp) {
        const int ki0 = kibase + 2 * jp, ki1 = ki0 + 1;
        float w0[16], w1[16];
#pragma unroll
        for (int d = 0; d < 16; ++d) {
            w0[d] = (ki0 < KI) ? Wp[d * (KI * O) + ki0 * O + o] : 0.f;
            w1[d] = (ki1 < KI) ? Wp[d * (KI * O) + ki1 * O + o] : 0.f;
        }
#pragma unroll
        for (int g = 0; g < G; ++g) {
            float s0 = 0.f, s1 = 0.f;
#pragma unroll
            for (int d = 0; d < 16; ++d) {
                const float e = El[g * 16 + d];
                s0 += e * w0[d]; s1 += e * w1[d];
            }
            pk[g][jp] = (unsigned int)f2bf(s0) | ((unsigned int)f2bf(s1) << 16);
        }
    }
#pragma unroll
    for (int g = 0; g < G; ++g) {
        uint4 v = make_uint4(pk[g][0], pk[g][1], pk[g][2], pk[g][3]);
        *(uint4*)&Wsw[((((size_t)(n0 + g) * NCT + ct) * KS + ks) * 64 + l) * 8] = v;
    }
}

// ---------------------------------------------------------------------------
// bf16 MFMA GEMM: C[2048][1152] = A[2048][2048] @ BT[1152][2048]^T
// 128x64 tile, BK=32, 4 waves (each 64x32 = 4x2 frags of 16x16x32)
// reg-staged LDS, pitch 40 u16 (2-way banks = free)
// ---------------------------------------------------------------------------
#define APITCH 40
__global__ __launch_bounds__(256) void gemm_bt(const u16* __restrict__ A,
                                               const u16* __restrict__ BT,
                                               u16* __restrict__ C)
{
    __shared__ u16 As[128 * APITCH];
    __shared__ u16 Bs[64 * APITCH];
    const int t = threadIdx.x, w = t >> 6, l = t & 63;
    const int m0 = blockIdx.y * 128, n0 = blockIdx.x * 64;
    const int wm = (w >> 1) * 64, wn = (w & 1) * 32;

    // staging map
    const int rA0 = t >> 2, rA1 = 64 + (t >> 2), qA = (t & 3) * 8;
    const int rB  = t >> 2;
    const size_t gA0 = (size_t)(m0 + rA0) * NN + qA;
    const size_t gA1 = (size_t)(m0 + rA1) * NN + qA;
    const size_t gB  = (size_t)(n0 + rB) * NN + qA;

    f32x4 acc[4][2];
#pragma unroll
    for (int i = 0; i < 4; ++i)
#pragma unroll
        for (int j = 0; j < 2; ++j) acc[i][j] = f32x4{0.f, 0.f, 0.f, 0.f};

    bf16x8 va0 = *(const bf16x8*)&A[gA0];
    bf16x8 va1 = *(const bf16x8*)&A[gA1];
    bf16x8 vb  = *(const bf16x8*)&BT[gB];

    for (int k0 = 0; k0 < NN; k0 += 32) {
        *(bf16x8*)&As[rA0 * APITCH + qA] = va0;
        *(bf16x8*)&As[rA1 * APITCH + qA] = va1;
        *(bf16x8*)&Bs[rB  * APITCH + qA] = vb;
        __syncthreads();
        if (k0 + 32 < NN) {
            va0 = *(const bf16x8*)&A[gA0 + k0 + 32];
            va1 = *(const bf16x8*)&A[gA1 + k0 + 32];
            vb  = *(const bf16x8*)&BT[gB + k0 + 32];
        }
        bf16x8 af[4], bfr[2];
#pragma unroll
        for (int mi = 0; mi < 4; ++mi)
            af[mi] = *(const bf16x8*)&As[(wm + mi * 16 + (l & 15)) * APITCH + (l >> 4) * 8];
#pragma unroll
        for (int nj = 0; nj < 2; ++nj)
            bfr[nj] = *(const bf16x8*)&Bs[(wn + nj * 16 + (l & 15)) * APITCH + (l >> 4) * 8];
#pragma unroll
        for (int mi = 0; mi < 4; ++mi)
#pragma unroll
            for (int nj = 0; nj < 2; ++nj)
                acc[mi][nj] = __builtin_amdgcn_mfma_f32_16x16x32_bf16(af[mi], bfr[nj], acc[mi][nj], 0, 0, 0);
        __syncthreads();
    }
#pragma unroll
    for (int mi = 0; mi < 4; ++mi)
#pragma unroll
        for (int nj = 0; nj < 2; ++nj)
#pragma unroll
            for (int q = 0; q < 4; ++q) {
                const int row = m0 + wm + mi * 16 + (l >> 4) * 4 + q;
                const int col = n0 + wn + nj * 16 + (l & 15);
                C[(size_t)row * NCP + col] = f2bf(acc[mi][nj][q]);
            }
}

// ---------------------------------------------------------------------------
// Gate apply: 4 nodes/block (1 wave each). A[16x132] in LDS (zero-padded),
// B-frags = coalesced b128 from Wsw. Bias fused. z*state->candRow, r->rbuf(bf16)
// ---------------------------------------------------------------------------
__global__ __launch_bounds__(256) void apply_gate(const u16* __restrict__ Wg,
                                                  const float* __restrict__ E,
                                                  const float* __restrict__ gb,
                                                  const float* __restrict__ X,
                                                  const float* __restrict__ state,
                                                  const u16* __restrict__ Zg,
                                                  u16* __restrict__ candRow,
                                                  u16* __restrict__ rbuf)
{
    const int t = threadIdx.x, wv = t >> 6, l = t & 63;
    const int node = blockIdx.x * 4 + wv;
    __shared__ u16 Al[4][16 * KIP];
    __shared__ float biasw[4][128];
    u16* base = Al[wv];

    // bias for this node
    {
        float b0 = 0.f, b1 = 0.f;
#pragma unroll
        for (int d = 0; d < 16; ++d) {
            const float e = E[node * 16 + d];
            b0 += e * gb[d * 128 + l];
            b1 += e * gb[d * 128 + 64 + l];
        }
        biasw[wv][l] = b0; biasw[wv][l + 64] = b1;
    }

    for (int i = l; i < 16 * KIP; i += 64) base[i] = 0;
    for (int f = l; f < 32; f += 64) {
        const int b = f >> 1, c = f & 1;
        base[b * KIP + c] = f2bf(X[(b * NN + node) * CINC + c]);
    }
#pragma unroll
    for (int k = 0; k < 16; ++k)
        base[k * KIP + 2 + l] = f2bf(state[(k * NN + node) * HID + l]);
    for (int f = l; f < NC; f += 64) {
        const int b = f / C1, i = f - b * C1;
        base[b * KIP + C1 + i] = Zg[(size_t)node * NCP + f];
    }
    __syncthreads();

    bf16x8 aF[KS];
#pragma unroll
    for (int kc = 0; kc < KS; ++kc)
        aF[kc] = *(const bf16x8*)&base[(l & 15) * KIP + kc * 32 + (l >> 4) * 8];

    const u16* wp_n = Wg + (((size_t)node * 8) * KS) * 512;
#pragma unroll 2
    for (int ct = 0; ct < 8; ++ct) {
        f32x4 acc = f32x4{0.f, 0.f, 0.f, 0.f};
#pragma unroll
        for (int kc = 0; kc < KS; ++kc) {
            bf16x8 bF = *(const bf16x8*)&wp_n[(((size_t)ct * KS + kc) * 64 + l) * 8];
            acc = __builtin_amdgcn_mfma_f32_16x16x32_bf16(aF[kc], bF, acc, 0, 0, 0);
        }
#pragma unroll
        for (int q = 0; q < 4; ++q) {
            const int b = (l >> 4) * 4 + q;
            const int o = ct * 16 + (l & 15);
            const float y = acc[q] + biasw[wv][o];
            const float sg = 1.f / (1.f + expf(-y));
            if (o < 64) {
                candRow[(size_t)node * NCP + b * C1 + CINC + o] =
                    f2bf(sg * state[(b * NN + node) * HID + o]);
            } else {
                rbuf[((size_t)node * BB + b) * HID + (o - 64)] = f2bf(sg);
            }
        }
    }
    for (int f = l; f < 32; f += 64) {
        const int b = f >> 1, c = f & 1;
        candRow[(size_t)node * NCP + b * C1 + c] = f2bf(X[(b * NN + node) * CINC + c]);
    }
}

// ---------------------------------------------------------------------------
// candT[j][m] = candRow[m][j]; rows j>=1056 zeroed
// ---------------------------------------------------------------------------
__global__ __launch_bounds__(256) void transpose_pad(const u16* __restrict__ in,
                                                     u16* __restrict__ out)
{
    __shared__ u16 tile[64][65];
    const int t = threadIdx.x;
    const int j0 = blockIdx.x * 64, m0 = blockIdx.y * 64;
    for (int r = t >> 6; r < 64; r += 4)
        tile[r][t & 63] = in[(size_t)(m0 + r) * NCP + j0 + (t & 63)];
    __syncthreads();
    for (int r = t >> 6; r < 64; r += 4) {
        const int j = j0 + r;
        const u16 val = (j < NC) ? tile[t & 63][r] : (u16)0;
        out[(size_t)j * NN + m0 + (t & 63)] = val;
    }
}

// ---------------------------------------------------------------------------
// Update apply + combine: hc=tanh(A@Wu+bias); h=r*state+(1-r)*hc
// ---------------------------------------------------------------------------
__global__ __launch_bounds__(256) void apply_upd(const u16* __restrict__ Wu,
                                                 const float* __restrict__ E,
                                                 const float* __restrict__ ub,
                                                 const u16* __restrict__ candRow,
                                                 const u16* __restrict__ Zu,
                                                 const float* __restrict__ state,
                                                 const u16* __restrict__ rbuf,
                                                 float* __restrict__ out)
{
    const int t = threadIdx.x, wv = t >> 6, l = t & 63;
    const int node = blockIdx.x * 4 + wv;
    __shared__ u16 Al[4][16 * KIP];
    __shared__ float biasw[4][64];
    u16* base = Al[wv];

    if (l < 64) {
        float b0 = 0.f;
#pragma unroll
        for (int d = 0; d < 16; ++d) b0 += E[node * 16 + d] * ub[d * 64 + l];
        biasw[wv][l] = b0;
    }

    for (int i = l; i < 16 * KIP; i += 64) base[i] = 0;
    for (int f = l; f < NC; f += 64) {
        const int b = f / C1, i = f - b * C1;
        base[b * KIP + i]      = candRow[(size_t)node * NCP + f];
        base[b * KIP + C1 + i] = Zu[(size_t)node * NCP + f];
    }
    __syncthreads();

    bf16x8 aF[KS];
#pragma unroll
    for (int kc = 0; kc < KS; ++kc)
        aF[kc] = *(const bf16x8*)&base[(l & 15) * KIP + kc * 32 + (l >> 4) * 8];

    const u16* wp_n = Wu + (((size_t)node * 4) * KS) * 512;
#pragma unroll 2
    for (int ct = 0; ct < 4; ++ct) {
        f32x4 acc = f32x4{0.f, 0.f, 0.f, 0.f};
#pragma unroll
        for (int kc = 0; kc < KS; ++kc) {
            bf16x8 bF = *(const bf16x8*)&wp_n[(((size_t)ct * KS + kc) * 64 + l) * 8];
            acc = __builtin_amdgcn_mfma_f32_16x16x32_bf16(aF[kc], bF, acc, 0, 0, 0);
        }
#pragma unroll
        for (int q = 0; q < 4; ++q) {
            const int b = (l >> 4) * 4 + q;
            const int o = ct * 16 + (l & 15);
            const float hc = tanhf(acc[q] + biasw[wv][o]);
            union { unsigned int u; float f; } rv;
            rv.u = ((unsigned int)rbuf[((size_t)node * BB + b) * HID + o]) << 16;
            const float r = rv.f;
            const float st = state[(b * NN + node) * HID + o];
            out[(size_t)(b * NN + node) * HID + o] = r * st + (1.f - r) * hc;
        }
    }
}

// ---------------------------------------------------------------------------
extern "C" void kernel_launch(void* const* d_in, const int* in_sizes, int n_in,
                              void* d_out, int out_size, void* d_ws, size_t ws_size,
                              hipStream_t stream)
{
    const float* X     = (const float*)d_in[0];
    const float* state = (const float*)d_in[1];
    const float* E     = (const float*)d_in[2];
    const float* gW    = (const float*)d_in[3];
    const float* gb    = (const float*)d_in[4];
    const float* uW    = (const float*)d_in[5];
    const float* ub    = (const float*)d_in[6];
    float* out = (float*)d_out;

    char* ws = (char*)d_ws;
    u16* S_bf  = (u16*)(ws);                    //  8,388,608
    u16* XcatT = (u16*)(ws + 8388608);          //  4,718,592 (reused as Zu)
    u16* Zg    = (u16*)(ws + 13107200);         //  4,718,592 (reused as candT)
    u16* candR = (u16*)(ws + 17825792);         //  4,718,592
    u16* rbuf  = (u16*)(ws + 22544384);         //  4,194,304
    u16* Wsw   = (u16*)(ws + 26738688);         // 83,886,080  -> total 110,624,768
    u16* candT = Zg;
    u16* Zu    = XcatT;

    support_softmax<<<NN, 256, 0, stream>>>(E, S_bf);
    build_xcatT<<<(NCP * NN) / 256, 256, 0, stream>>>(X, state, XcatT);
    wbuild_sw<8><<<dim3(10, 256), 256, 0, stream>>>(E, gW, Wsw);
    gemm_bt<<<dim3(NCP / 64, NN / 128), 256, 0, stream>>>(S_bf, XcatT, Zg);
    apply_gate<<<NN / 4, 256, 0, stream>>>(Wsw, E, gb, X, state, Zg, candR, rbuf);
    transpose_pad<<<dim3(NCP / 64, NN / 64), 256, 0, stream>>>(candR, candT);
    wbuild_sw<4><<<dim3(5, 256), 256, 0, stream>>>(E, uW, Wsw);
    gemm_bt<<<dim3(NCP / 64, NN / 128), 256, 0, stream>>>(S_bf, candT, Zu);
    apply_upd<<<NN / 4, 256, 0, stream>>>(Wsw, E, ub, candR, Zu, state, rbuf, out);
}

// Round 15
// 291.862 us; speedup vs baseline: 1.6043x; 1.1272x over previous
//
#include <hip/hip_runtime.h>
#include <math.h>

#define NN   2048
#define BB   16
#define CINC 2
#define HID  64
#define C1   66
#define NC   1056      // 16*66
#define NCP  1152      // padded col dim
#define KI   132       // contraction length
#define KIP  168       // LDS A row pitch (u16)
#define KS   5         // K fragments of 32 (132 -> 160 padded)

typedef unsigned short u16;
typedef __attribute__((ext_vector_type(8))) short bf16x8;
typedef __attribute__((ext_vector_type(4))) float f32x4;

__device__ __forceinline__ u16 f2bf(float f) {
    union { float f; unsigned int u; } v; v.f = f;
    unsigned int r = (v.u + 0x7FFFu + ((v.u >> 16) & 1u)) >> 16;
    return (u16)r;
}

// ---------------------------------------------------------------------------
// S_bf[n][m] = softmax_m(relu(E@E^T)) in bf16
// ---------------------------------------------------------------------------
__global__ __launch_bounds__(256) void support_softmax(const float* __restrict__ E,
                                                       u16* __restrict__ S)
{
    const int n = blockIdx.x, t = threadIdx.x;
    __shared__ float red[4];
    float en[16];
#pragma unroll
    for (int d = 0; d < 16; ++d) en[d] = E[n * 16 + d];

    float v[8]; float mx = 0.f;
#pragma unroll
    for (int j = 0; j < 8; ++j) {
        const int m = t + j * 256;
        const float4* ep = (const float4*)&E[m * 16];
        float4 e0 = ep[0], e1 = ep[1], e2 = ep[2], e3 = ep[3];
        float dot = en[0]*e0.x + en[1]*e0.y + en[2]*e0.z + en[3]*e0.w
                  + en[4]*e1.x + en[5]*e1.y + en[6]*e1.z + en[7]*e1.w
                  + en[8]*e2.x + en[9]*e2.y + en[10]*e2.z + en[11]*e2.w
                  + en[12]*e3.x + en[13]*e3.y + en[14]*e3.z + en[15]*e3.w;
        dot = fmaxf(dot, 0.f);
        v[j] = dot; mx = fmaxf(mx, dot);
    }
#pragma unroll
    for (int off = 32; off; off >>= 1) mx = fmaxf(mx, __shfl_down(mx, off, 64));
    const int wid = t >> 6, lane = t & 63;
    if (lane == 0) red[wid] = mx;
    __syncthreads();
    mx = fmaxf(fmaxf(red[0], red[1]), fmaxf(red[2], red[3]));

    float s = 0.f;
#pragma unroll
    for (int j = 0; j < 8; ++j) { v[j] = expf(v[j] - mx); s += v[j]; }
#pragma unroll
    for (int off = 32; off; off >>= 1) s += __shfl_down(s, off, 64);
    __syncthreads();
    if (lane == 0) red[wid] = s;
    __syncthreads();
    s = red[0] + red[1] + red[2] + red[3];
    const float inv = 1.f / s;
#pragma unroll
    for (int j = 0; j < 8; ++j) S[n * NN + t + j * 256] = f2bf(v[j] * inv);
}

// ---------------------------------------------------------------------------
// XcatT[j][m] (bf16, [1152][2048]); rows j>=1056 zero
// ---------------------------------------------------------------------------
__global__ __launch_bounds__(256) void build_xcatT(const float* __restrict__ X,
                                                   const float* __restrict__ state,
                                                   u16* __restrict__ XT)
{
    const int idx = blockIdx.x * 256 + threadIdx.x;
    const int m = idx & (NN - 1), j = idx >> 11;
    float val = 0.f;
    if (j < NC) {
        const int b = j / C1, c = j - b * C1;
        val = (c < CINC) ? X[(b * NN + m) * CINC + c]
                         : state[(b * NN + m) * HID + (c - CINC)];
    }
    XT[(size_t)j * NN + m] = f2bf(val);
}

// ---------------------------------------------------------------------------
// wp_transpose: Wt[f][d] = Wp[d][f], f in [0,F), d in [0,16). 64-f tile/block.
// Makes the per-(ki,o) weight vector d-contiguous (64B) for wbuild_sw.
// ---------------------------------------------------------------------------
__global__ __launch_bounds__(256) void wp_transpose(const float* __restrict__ Wp,
                                                    float* __restrict__ Wt, int F)
{
    __shared__ float tile[64][17];
    const int f0 = blockIdx.x * 64;
    const int t = threadIdx.x;
    const int fr = t & 63, dr = t >> 6;
#pragma unroll
    for (int p = 0; p < 4; ++p)
        tile[fr][dr + p * 4] = Wp[(size_t)(dr + p * 4) * F + f0 + fr];
    __syncthreads();
    const int fw = t >> 2, dq = (t & 3) * 4;
    float4 v = make_float4(tile[fw][dq], tile[fw][dq + 1], tile[fw][dq + 2], tile[fw][dq + 3]);
    *(float4*)&Wt[(size_t)(f0 + fw) * 16 + dq] = v;
}

// ---------------------------------------------------------------------------
// wbuild_sw<NCT>: Wsw[n][ct][ks][lane][8] bf16 fragment-swizzled per-node W.
// element (n,ct,ks,l,j) = sum_d E[n,d]*Wt[ki*O+o][d], ki=ks*32+(l>>4)*8+j,
// o=ct*16+(l&15); zero if ki>=132. G=8 nodes per blockIdx.y.
// Loads are 4x float4 (d-contiguous via Wt). pk strictly register-resident.
// (ki0 even => ki1=ki0+1 in-bounds iff ki0 in-bounds, since KI=132 even.)
// ---------------------------------------------------------------------------
template<int NCT>
__global__ __launch_bounds__(256) void wbuild_sw(const float* __restrict__ E,
                                                 const float* __restrict__ Wt,
                                                 u16* __restrict__ Wsw)
{
    const int G = 8;
    const int t = threadIdx.x;
    const int slot = blockIdx.x * 256 + t;         // over NCT*5*64
    const int l = slot & 63, ks = (slot >> 6) % KS, ct = slot / (KS * 64);
    const int n0 = blockIdx.y * G;
    const int O = NCT * 16;
    __shared__ float El[G * 16];
    if (t < G * 16) El[t] = E[n0 * 16 + t];
    __syncthreads();

    const int o = ct * 16 + (l & 15);
    const int kibase = ks * 32 + (l >> 4) * 8;

    unsigned int pk[G][4];
#pragma unroll
    for (int jp = 0; jp < 4; ++jp) {
        const int ki0 = kibase + 2 * jp, ki1 = ki0 + 1;
        float4 a0, a1, a2, a3, b0, b1, b2, b3;
        if (ki0 < KI) {
            const float4* pa = (const float4*)&Wt[((size_t)ki0 * O + o) * 16];
            const float4* pb = (const float4*)&Wt[((size_t)ki1 * O + o) * 16];
            a0 = pa[0]; a1 = pa[1]; a2 = pa[2]; a3 = pa[3];
            b0 = pb[0]; b1 = pb[1]; b2 = pb[2]; b3 = pb[3];
        } else {
            a0 = a1 = a2 = a3 = make_float4(0.f, 0.f, 0.f, 0.f);
            b0 = b1 = b2 = b3 = make_float4(0.f, 0.f, 0.f, 0.f);
        }
#pragma unroll
        for (int g = 0; g < G; ++g) {
            const float* e = &El[g * 16];
            float s0 = e[0]*a0.x + e[1]*a0.y + e[2]*a0.z + e[3]*a0.w
                     + e[4]*a1.x + e[5]*a1.y + e[6]*a1.z + e[7]*a1.w
                     + e[8]*a2.x + e[9]*a2.y + e[10]*a2.z + e[11]*a2.w
                     + e[12]*a3.x + e[13]*a3.y + e[14]*a3.z + e[15]*a3.w;
            float s1 = e[0]*b0.x + e[1]*b0.y + e[2]*b0.z + e[3]*b0.w
                     + e[4]*b1.x + e[5]*b1.y + e[6]*b1.z + e[7]*b1.w
                     + e[8]*b2.x + e[9]*b2.y + e[10]*b2.z + e[11]*b2.w
                     + e[12]*b3.x + e[13]*b3.y + e[14]*b3.z + e[15]*b3.w;
            pk[g][jp] = (unsigned int)f2bf(s0) | ((unsigned int)f2bf(s1) << 16);
        }
    }
#pragma unroll
    for (int g = 0; g < G; ++g) {
        uint4 v = make_uint4(pk[g][0], pk[g][1], pk[g][2], pk[g][3]);
        *(uint4*)&Wsw[((((size_t)(n0 + g) * NCT + ct) * KS + ks) * 64 + l) * 8] = v;
    }
}

// ---------------------------------------------------------------------------
// bf16 MFMA GEMM: C[2048][1152] = A[2048][2048] @ BT[1152][2048]^T
// 128x64 tile, BK=32, 4 waves (each 64x32 = 4x2 frags of 16x16x32)
// reg-staged LDS, pitch 40 u16 (2-way banks = free)
// ---------------------------------------------------------------------------
#define APITCH 40
__global__ __launch_bounds__(256) void gemm_bt(const u16* __restrict__ A,
                                               const u16* __restrict__ BT,
                                               u16* __restrict__ C)
{
    __shared__ u16 As[128 * APITCH];
    __shared__ u16 Bs[64 * APITCH];
    const int t = threadIdx.x, w = t >> 6, l = t & 63;
    const int m0 = blockIdx.y * 128, n0 = blockIdx.x * 64;
    const int wm = (w >> 1) * 64, wn = (w & 1) * 32;

    // staging map
    const int rA0 = t >> 2, rA1 = 64 + (t >> 2), qA = (t & 3) * 8;
    const int rB  = t >> 2;
    const size_t gA0 = (size_t)(m0 + rA0) * NN + qA;
    const size_t gA1 = (size_t)(m0 + rA1) * NN + qA;
    const size_t gB  = (size_t)(n0 + rB) * NN + qA;

    f32x4 acc[4][2];
#pragma unroll
    for (int i = 0; i < 4; ++i)
#pragma unroll
        for (int j = 0; j < 2; ++j) acc[i][j] = f32x4{0.f, 0.f, 0.f, 0.f};

    bf16x8 va0 = *(const bf16x8*)&A[gA0];
    bf16x8 va1 = *(const bf16x8*)&A[gA1];
    bf16x8 vb  = *(const bf16x8*)&BT[gB];

    for (int k0 = 0; k0 < NN; k0 += 32) {
        *(bf16x8*)&As[rA0 * APITCH + qA] = va0;
        *(bf16x8*)&As[rA1 * APITCH + qA] = va1;
        *(bf16x8*)&Bs[rB  * APITCH + qA] = vb;
        __syncthreads();
        if (k0 + 32 < NN) {
            va0 = *(const bf16x8*)&A[gA0 + k0 + 32];
            va1 = *(const bf16x8*)&A[gA1 + k0 + 32];
            vb  = *(const bf16x8*)&BT[gB + k0 + 32];
        }
        bf16x8 af[4], bfr[2];
#pragma unroll
        for (int mi = 0; mi < 4; ++mi)
            af[mi] = *(const bf16x8*)&As[(wm + mi * 16 + (l & 15)) * APITCH + (l >> 4) * 8];
#pragma unroll
        for (int nj = 0; nj < 2; ++nj)
            bfr[nj] = *(const bf16x8*)&Bs[(wn + nj * 16 + (l & 15)) * APITCH + (l >> 4) * 8];
#pragma unroll
        for (int mi = 0; mi < 4; ++mi)
#pragma unroll
            for (int nj = 0; nj < 2; ++nj)
                acc[mi][nj] = __builtin_amdgcn_mfma_f32_16x16x32_bf16(af[mi], bfr[nj], acc[mi][nj], 0, 0, 0);
        __syncthreads();
    }
#pragma unroll
    for (int mi = 0; mi < 4; ++mi)
#pragma unroll
        for (int nj = 0; nj < 2; ++nj)
#pragma unroll
            for (int q = 0; q < 4; ++q) {
                const int row = m0 + wm + mi * 16 + (l >> 4) * 4 + q;
                const int col = n0 + wn + nj * 16 + (l & 15);
                C[(size_t)row * NCP + col] = f2bf(acc[mi][nj][q]);
            }
}

// ---------------------------------------------------------------------------
// Gate apply: 4 nodes/block (1 wave each). A[16x132] in LDS (zero-padded),
// B-frags = coalesced b128 from Wsw. Bias fused. z*state->candRow, r->rbuf(bf16)
// ---------------------------------------------------------------------------
__global__ __launch_bounds__(256) void apply_gate(const u16* __restrict__ Wg,
                                                  const float* __restrict__ E,
                                                  const float* __restrict__ gb,
                                                  const float* __restrict__ X,
                                                  const float* __restrict__ state,
                                                  const u16* __restrict__ Zg,
                                                  u16* __restrict__ candRow,
                                                  u16* __restrict__ rbuf)
{
    const int t = threadIdx.x, wv = t >> 6, l = t & 63;
    const int node = blockIdx.x * 4 + wv;
    __shared__ u16 Al[4][16 * KIP];
    __shared__ float biasw[4][128];
    u16* base = Al[wv];

    // bias for this node
    {
        float b0 = 0.f, b1 = 0.f;
#pragma unroll
        for (int d = 0; d < 16; ++d) {
            const float e = E[node * 16 + d];
            b0 += e * gb[d * 128 + l];
            b1 += e * gb[d * 128 + 64 + l];
        }
        biasw[wv][l] = b0; biasw[wv][l + 64] = b1;
    }

    for (int i = l; i < 16 * KIP; i += 64) base[i] = 0;
    for (int f = l; f < 32; f += 64) {
        const int b = f >> 1, c = f & 1;
        base[b * KIP + c] = f2bf(X[(b * NN + node) * CINC + c]);
    }
#pragma unroll
    for (int k = 0; k < 16; ++k)
        base[k * KIP + 2 + l] = f2bf(state[(k * NN + node) * HID + l]);
    for (int f = l; f < NC; f += 64) {
        const int b = f / C1, i = f - b * C1;
        base[b * KIP + C1 + i] = Zg[(size_t)node * NCP + f];
    }
    __syncthreads();

    bf16x8 aF[KS];
#pragma unroll
    for (int kc = 0; kc < KS; ++kc)
        aF[kc] = *(const bf16x8*)&base[(l & 15) * KIP + kc * 32 + (l >> 4) * 8];

    const u16* wp_n = Wg + (((size_t)node * 8) * KS) * 512;
#pragma unroll 2
    for (int ct = 0; ct < 8; ++ct) {
        f32x4 acc = f32x4{0.f, 0.f, 0.f, 0.f};
#pragma unroll
        for (int kc = 0; kc < KS; ++kc) {
            bf16x8 bF = *(const bf16x8*)&wp_n[(((size_t)ct * KS + kc) * 64 + l) * 8];
            acc = __builtin_amdgcn_mfma_f32_16x16x32_bf16(aF[kc], bF, acc, 0, 0, 0);
        }
#pragma unroll
        for (int q = 0; q < 4; ++q) {
            const int b = (l >> 4) * 4 + q;
            const int o = ct * 16 + (l & 15);
            const float y = acc[q] + biasw[wv][o];
            const float sg = 1.f / (1.f + expf(-y));
            if (o < 64) {
                candRow[(size_t)node * NCP + b * C1 + CINC + o] =
                    f2bf(sg * state[(b * NN + node) * HID + o]);
            } else {
                rbuf[((size_t)node * BB + b) * HID + (o - 64)] = f2bf(sg);
            }
        }
    }
    for (int f = l; f < 32; f += 64) {
        const int b = f >> 1, c = f & 1;
        candRow[(size_t)node * NCP + b * C1 + c] = f2bf(X[(b * NN + node) * CINC + c]);
    }
}

// ---------------------------------------------------------------------------
// candT[j][m] = candRow[m][j]; rows j>=1056 zeroed
// ---------------------------------------------------------------------------
__global__ __launch_bounds__(256) void transpose_pad(const u16* __restrict__ in,
                                                     u16* __restrict__ out)
{
    __shared__ u16 tile[64][65];
    const int t = threadIdx.x;
    const int j0 = blockIdx.x * 64, m0 = blockIdx.y * 64;
    for (int r = t >> 6; r < 64; r += 4)
        tile[r][t & 63] = in[(size_t)(m0 + r) * NCP + j0 + (t & 63)];
    __syncthreads();
    for (int r = t >> 6; r < 64; r += 4) {
        const int j = j0 + r;
        const u16 val = (j < NC) ? tile[t & 63][r] : (u16)0;
        out[(size_t)j * NN + m0 + (t & 63)] = val;
    }
}

// ---------------------------------------------------------------------------
// Update apply + combine: hc=tanh(A@Wu+bias); h=r*state+(1-r)*hc
// ---------------------------------------------------------------------------
__global__ __launch_bounds__(256) void apply_upd(const u16* __restrict__ Wu,
                                                 const float* __restrict__ E,
                                                 const float* __restrict__ ub,
                                                 const u16* __restrict__ candRow,
                                                 const u16* __restrict__ Zu,
                                                 const float* __restrict__ state,
                                                 const u16* __restrict__ rbuf,
                                                 float* __restrict__ out)
{
    const int t = threadIdx.x, wv = t >> 6, l = t & 63;
    const int node = blockIdx.x * 4 + wv;
    __shared__ u16 Al[4][16 * KIP];
    __shared__ float biasw[4][64];
    u16* base = Al[wv];

    if (l < 64) {
        float b0 = 0.f;
#pragma unroll
        for (int d = 0; d < 16; ++d) b0 += E[node * 16 + d] * ub[d * 64 + l];
        biasw[wv][l] = b0;
    }

    for (int i = l; i < 16 * KIP; i += 64) base[i] = 0;
    for (int f = l; f < NC; f += 64) {
        const int b = f / C1, i = f - b * C1;
        base[b * KIP + i]      = candRow[(size_t)node * NCP + f];
        base[b * KIP + C1 + i] = Zu[(size_t)node * NCP + f];
    }
    __syncthreads();

    bf16x8 aF[KS];
#pragma unroll
    for (int kc = 0; kc < KS; ++kc)
        aF[kc] = *(const bf16x8*)&base[(l & 15) * KIP + kc * 32 + (l >> 4) * 8];

    const u16* wp_n = Wu + (((size_t)node * 4) * KS) * 512;
#pragma unroll 2
    for (int ct = 0; ct < 4; ++ct) {
        f32x4 acc = f32x4{0.f, 0.f, 0.f, 0.f};
#pragma unroll
        for (int kc = 0; kc < KS; ++kc) {
            bf16x8 bF = *(const bf16x8*)&wp_n[(((size_t)ct * KS + kc) * 64 + l) * 8];
            acc = __builtin_amdgcn_mfma_f32_16x16x32_bf16(aF[kc], bF, acc, 0, 0, 0);
        }
#pragma unroll
        for (int q = 0; q < 4; ++q) {
            const int b = (l >> 4) * 4 + q;
            const int o = ct * 16 + (l & 15);
            const float hc = tanhf(acc[q] + biasw[wv][o]);
            union { unsigned int u; float f; } rv;
            rv.u = ((unsigned int)rbuf[((size_t)node * BB + b) * HID + o]) << 16;
            const float r = rv.f;
            const float st = state[(b * NN + node) * HID + o];
            out[(size_t)(b * NN + node) * HID + o] = r * st + (1.f - r) * hc;
        }
    }
}

// ---------------------------------------------------------------------------
extern "C" void kernel_launch(void* const* d_in, const int* in_sizes, int n_in,
                              void* d_out, int out_size, void* d_ws, size_t ws_size,
                              hipStream_t stream)
{
    const float* X     = (const float*)d_in[0];
    const float* state = (const float*)d_in[1];
    const float* E     = (const float*)d_in[2];
    const float* gW    = (const float*)d_in[3];
    const float* gb    = (const float*)d_in[4];
    const float* uW    = (const float*)d_in[5];
    const float* ub    = (const float*)d_in[6];
    float* out = (float*)d_out;

    char* ws = (char*)d_ws;
    u16* S_bf  = (u16*)(ws);                    //  8,388,608
    u16* XcatT = (u16*)(ws + 8388608);          //  4,718,592 (reused as Wt_upd, then Zu)
    u16* Zg    = (u16*)(ws + 13107200);         //  4,718,592 (reused as candT)
    u16* candR = (u16*)(ws + 17825792);         //  4,718,592 (first hosts Wt_gate)
    u16* rbuf  = (u16*)(ws + 22544384);         //  4,194,304
    u16* Wsw   = (u16*)(ws + 26738688);         // 83,886,080  -> total 110,624,768
    u16* candT = Zg;
    u16* Zu    = XcatT;
    float* Wt_gate = (float*)candR;             // 1,081,344 B; dead before apply_gate
    float* Wt_upd  = (float*)XcatT;             //   540,672 B; dead after gemm#1, before gemm#2

    support_softmax<<<NN, 256, 0, stream>>>(E, S_bf);
    build_xcatT<<<(NCP * NN) / 256, 256, 0, stream>>>(X, state, XcatT);
    wp_transpose<<<(KI * 128) / 64, 256, 0, stream>>>(gW, Wt_gate, KI * 128);
    wbuild_sw<8><<<dim3(10, 256), 256, 0, stream>>>(E, Wt_gate, Wsw);
    gemm_bt<<<dim3(NCP / 64, NN / 128), 256, 0, stream>>>(S_bf, XcatT, Zg);
    apply_gate<<<NN / 4, 256, 0, stream>>>(Wsw, E, gb, X, state, Zg, candR, rbuf);
    wp_transpose<<<(KI * 64) / 64, 256, 0, stream>>>(uW, Wt_upd, KI * 64);
    transpose_pad<<<dim3(NCP / 64, NN / 64), 256, 0, stream>>>(candR, candT);
    wbuild_sw<4><<<dim3(5, 256), 256, 0, stream>>>(E, Wt_upd, Wsw);
    gemm_bt<<<dim3(NCP / 64, NN / 128), 256, 0, stream>>>(S_bf, candT, Zu);
    apply_upd<<<NN / 4, 256, 0, stream>>>(Wsw, E, ub, candR, Zu, state, rbuf, out);
}